// Round 6
// baseline (363.210 us; speedup 1.0000x reference)
//
#include <hip/hip_runtime.h>
#include <hip/hip_bf16.h>
#include <math.h>

// B=8, H=W=128, C=hidden=256, N=16384, Mtot=131072.
#define Hc   128
#define Wc   128
#define Cc   256
#define Nc   (Hc * Wc)
#define Bn   8
#define Mtot (Bn * Nc)          // 131072
#define CSZ  52                 // ceil(256/5)
#define SPAD 2

typedef unsigned short ushort4v __attribute__((ext_vector_type(4)));
typedef unsigned short ushort8  __attribute__((ext_vector_type(8)));
typedef __bf16         bf16x8   __attribute__((ext_vector_type(8)));
typedef float          f32x4    __attribute__((ext_vector_type(4)));

__device__ __forceinline__ float bf2f(unsigned short u) {
    return __uint_as_float(((unsigned)u) << 16);
}
__device__ __forceinline__ unsigned short f2bf(float f) {   // RNE
    unsigned u = __float_as_uint(f);
    return (unsigned short)((u + 0x7fffu + ((u >> 16) & 1u)) >> 16);
}
// pack two floats -> two bf16 (a -> low16). Round-half-up (ok vs bf16 eps).
__device__ __forceinline__ unsigned pk2bf(float a, float b) {
    unsigned ua = __float_as_uint(a) + 0x8000u;
    unsigned ub = __float_as_uint(b) + 0x8000u;
    return __builtin_amdgcn_perm(ub, ua, 0x07060302);
}
__device__ __forceinline__ void async16(const void* g, void* l) {
    __builtin_amdgcn_global_load_lds(
        (const __attribute__((address_space(1))) unsigned*)g,
        (__attribute__((address_space(3))) unsigned*)l, 16, 0, 0);
}

// ---------------------------------------------------------------------------
// P0: w1, w2 fp32 -> bf16; dw_w [ch][tap] -> dwT [tap][ch] fp32.
// All prep outputs live in d_ws (past the 128 MB h1/xb region).
// ---------------------------------------------------------------------------
__global__ __launch_bounds__(256)
void wprep_kernel(const float* __restrict__ w1, const float* __restrict__ w2,
                  const float* __restrict__ dw_w,
                  unsigned short* __restrict__ w1b, unsigned short* __restrict__ w2b,
                  float* __restrict__ dwT)
{
    const int g = blockIdx.x * 256 + threadIdx.x;   // 16384 threads
    {
        float4 a = *(const float4*)(w1 + (size_t)g * 4);
        ushort4v o = { f2bf(a.x), f2bf(a.y), f2bf(a.z), f2bf(a.w) };
        *(ushort4v*)(w1b + (size_t)g * 4) = o;
    }
    {
        float4 a = *(const float4*)(w2 + (size_t)g * 4);
        ushort4v o = { f2bf(a.x), f2bf(a.y), f2bf(a.z), f2bf(a.w) };
        *(ushort4v*)(w2b + (size_t)g * 4) = o;
    }
    if (g < 9 * Cc) dwT[(g % 9) * Cc + g / 9] = dw_w[g];
}

// ---------------------------------------------------------------------------
// P1: H-shift + fp32->bf16 convert, gather form: xb[(b,h,w)][c] =
// (0 <= h - s_c < H) ? bf16(x[(b, h-s_c, w)][c]) : 0.   s_c = c/52 - 2.
// 8 channels/thread; a 4-chunk never crosses a 52-boundary.
// ---------------------------------------------------------------------------
__global__ __launch_bounds__(256)
void shiftcvt_kernel(const float* __restrict__ x, unsigned short* __restrict__ xb)
{
    const int gid0 = blockIdx.x * 256 + threadIdx.x;
#pragma unroll
    for (int it = 0; it < 4; ++it) {
        const int gid = gid0 + it * (4096 * 256);   // 4.19M chunks total
        const int row = gid >> 5;                   // b*16384 + h*128 + w
        const int c   = (gid & 31) * 8;
        const int hh  = (row >> 7) & 127;
        const int s0  = c / CSZ - SPAD;
        const int s1  = (c + 4) / CSZ - SPAD;
        const int h0  = hh - s0, h1r = hh - s1;
        float4 v0 = make_float4(0.f, 0.f, 0.f, 0.f);
        float4 v1 = make_float4(0.f, 0.f, 0.f, 0.f);
        if (h0  >= 0 && h0  < Hc)
            v0 = *(const float4*)(x + ((size_t)row + (size_t)(h0 - hh) * Wc) * Cc + c);
        if (h1r >= 0 && h1r < Hc)
            v1 = *(const float4*)(x + ((size_t)row + (size_t)(h1r - hh) * Wc) * Cc + c + 4);
        uint4 o;
        o.x = pk2bf(v0.x, v0.y); o.y = pk2bf(v0.z, v0.w);
        o.z = pk2bf(v1.x, v1.y); o.w = pk2bf(v1.z, v1.w);
        *(uint4*)(xb + (size_t)row * Cc + c) = o;
    }
}

// ---------------------------------------------------------------------------
// K1: h1 = x_shifted_bf16 @ w1^T + b1. Pure bf16 GEMM, both panels async16,
// single-barrier 1-step-lookahead, LDS 34816 (Cs unions) -> 4 blocks/CU.
// ---------------------------------------------------------------------------
__global__ __launch_bounds__(256)
void fc1_mfma_kernel(const unsigned short* __restrict__ xb, const unsigned short* __restrict__ w1b,
                     const float* __restrict__ b1, unsigned short* __restrict__ h1)
{
    __shared__ __align__(16) unsigned char smem[34816];
    __bf16* As = (__bf16*)smem;                     // [2][128][32]
    __bf16* Bs = (__bf16*)(smem + 16384);           // [2][128][32]
    unsigned short* Cs = (unsigned short*)smem;     // [128][136] epilogue

    const int tid  = threadIdx.x;
    const int lane = tid & 63;
    const int wave = tid >> 6;
    const int wm = (wave >> 1) * 64, wn = (wave & 1) * 64;

    // nwg = 2048 (div by 8): bijective XCD swizzle.
    const int lid = ((blockIdx.x & 7) << 8) | (blockIdx.x >> 3);
    const int bx  = lid >> 1;                  // b*128 + h
    const int j0  = (lid & 1) * 128;
    const size_t m0 = (size_t)bx * 128;
    const int idx0 = tid, idx1 = tid + 256;    // 16B chunks per panel

    const size_t aro0 = (m0 + (idx0 >> 2)) * Cc + (idx0 & 3) * 8;
    const size_t aro1 = (m0 + (idx1 >> 2)) * Cc + (idx1 & 3) * 8;
    const size_t bro0 = (size_t)(j0 + (idx0 >> 2)) * Cc + (idx0 & 3) * 8;
    const size_t bro1 = (size_t)(j0 + (idx1 >> 2)) * Cc + (idx1 & 3) * 8;

    auto stage = [&](int buf, int t) {
        const int k0 = t * 32;
        __bf16* adst = As + buf * 4096;
        __bf16* bdst = Bs + buf * 4096;
        async16(xb  + aro0 + k0, adst + idx0 * 8);
        async16(xb  + aro1 + k0, adst + idx1 * 8);
        async16(w1b + bro0 + k0, bdst + idx0 * 8);
        async16(w1b + bro1 + k0, bdst + idx1 * 8);
    };

    f32x4 acc[4][4] = {};
    const int kq = (lane >> 4) * 8;
    const int rr = lane & 15;

    stage(0, 0);
    __syncthreads();

    int cur = 0;
    for (int t = 0; t < 8; ++t) {
        const int nxt = cur ^ 1;
        if (t < 7) stage(nxt, t + 1);   // issue next tile BEFORE compute
        bf16x8 a[4], b[4];
        const __bf16* ap = As + cur * 4096;
        const __bf16* bp = Bs + cur * 4096;
#pragma unroll
        for (int i = 0; i < 4; ++i) {
            a[i] = *(const bf16x8*)(ap + (wm + i * 16 + rr) * 32 + kq);
            b[i] = *(const bf16x8*)(bp + (wn + i * 16 + rr) * 32 + kq);
        }
#pragma unroll
        for (int i = 0; i < 4; ++i)
#pragma unroll
            for (int j = 0; j < 4; ++j)
                acc[i][j] = __builtin_amdgcn_mfma_f32_16x16x32_bf16(a[i], b[j], acc[i][j], 0, 0, 0);
        __syncthreads();                // drains next-tile loads (m97 structure)
        cur = nxt;
    }

    const int cq = (lane >> 4) * 4;
    const int cc = lane & 15;
    float bv[4];
#pragma unroll
    for (int j = 0; j < 4; ++j) bv[j] = b1[j0 + wn + j * 16 + cc];
#pragma unroll
    for (int i = 0; i < 4; ++i)
#pragma unroll
        for (int j = 0; j < 4; ++j) {
            const int col = wn + j * 16 + cc;
#pragma unroll
            for (int rg = 0; rg < 4; ++rg)
                Cs[(wm + i * 16 + cq + rg) * 136 + col] = f2bf(acc[i][j][rg] + bv[j]);
        }
    __syncthreads();
    {
        const int row = tid >> 1, hf = tid & 1;
        const unsigned short* src = Cs + row * 136 + hf * 64;
        unsigned short* dst = h1 + (m0 + row) * Cc + j0 + hf * 64;
#pragma unroll
        for (int i = 0; i < 8; ++i)
            *(uint4*)(dst + i * 8) = *(const uint4*)(src + i * 8);
    }
}

// ---------------------------------------------------------------------------
// K2: FUSED depthwise3x3 + bias + GELU + W-shift + fc2 GEMM + b2.
// One block per (b,h) row (grid 1024). The W-shift permutes only within the
// row's 128 w-positions, so the shifted GELU row IS this block's fc2 A-tile:
//   phase 0: zero 64 KB LDS A-tile
//   phase 1: dwconv row (4 quarter passes, old dwconv mapping), gelu, scatter
//            bf16 into LDS A at (w+s_c, c) with byte-XOR ((w&7)<<4) swizzle
//            (borders remain zero = zero_borders semantics)
//   phase 2: out[m0+*][j] = A @ w2b^T + b2, two j0 passes of 128 cols,
//            w2b staged via async16 double-buffer (same loop as old fc2).
// Kills gsh (67 MB write + 67 MB read), zero_borders, and one launch.
// LDS 81920 B -> exactly 2 blocks/CU. XOR read-side folds to lane constant.
// ---------------------------------------------------------------------------
__global__ __launch_bounds__(256)
void dwfc2_kernel(const unsigned short* __restrict__ h1,
                  const float* __restrict__ dwT, const float* __restrict__ dw_b,
                  const unsigned short* __restrict__ w2b, const float* __restrict__ b2,
                  float* __restrict__ out)
{
    __shared__ __align__(16) unsigned char smem[81920];
    unsigned char* Ash = smem;                 // [128 rows][512 B] XOR-swizzled
    __bf16* Bs = (__bf16*)(smem + 65536);      // [2][128][32]

    const int tid  = threadIdx.x;
    const int lane = tid & 63;
    const int wave = tid >> 6;

    // grid 1024 (div by 8): bijective XCD swizzle; adjacent lid share h1 rows.
    const int lid = ((blockIdx.x & 7) << 7) | (blockIdx.x >> 3);
    const int bb = lid >> 7, hh = lid & 127;
    const size_t m0 = (size_t)lid * 128;

    // ---- phase 0: zero A-tile (256 B per thread) ----
    {
        uint4 z; z.x = z.y = z.z = z.w = 0u;
        unsigned char* p = Ash + tid * 256;
#pragma unroll
        for (int i = 0; i < 16; ++i) *(uint4*)(p + i * 16) = z;
    }
    __syncthreads();

    // ---- phase 1: dwconv + gelu + W-shift scatter into LDS ----
    {
        const int cg = tid & 31;          // channel group (8 ch)
        const int wq = tid >> 5;          // w-quad 0..7 within quarter
        const int c0 = cg * 8;
        const int s0 = c0 / CSZ - SPAD;
        const int s1 = (c0 + 4) / CSZ - SPAD;

        float bias[8];
        {
            float4 a0 = *(const float4*)(dw_b + c0);
            float4 a1 = *(const float4*)(dw_b + c0 + 4);
            bias[0] = a0.x; bias[1] = a0.y; bias[2] = a0.z; bias[3] = a0.w;
            bias[4] = a1.x; bias[5] = a1.y; bias[6] = a1.z; bias[7] = a1.w;
        }
        float wt[3][3][8];
#pragma unroll
        for (int dy = 0; dy < 3; ++dy)
#pragma unroll
            for (int tx = 0; tx < 3; ++tx) {
                const float* wp = dwT + (dy * 3 + tx) * Cc + c0;
                float4 wa = *(const float4*)(wp);
                float4 wb = *(const float4*)(wp + 4);
                wt[dy][tx][0] = wa.x; wt[dy][tx][1] = wa.y;
                wt[dy][tx][2] = wa.z; wt[dy][tx][3] = wa.w;
                wt[dy][tx][4] = wb.x; wt[dy][tx][5] = wb.y;
                wt[dy][tx][6] = wb.z; wt[dy][tx][7] = wb.w;
            }

#pragma unroll 1
        for (int qtr = 0; qtr < 4; ++qtr) {
            const int wbase = qtr * 32 + wq * 4 - 1;
            float acc[4][8];
#pragma unroll
            for (int i = 0; i < 4; ++i)
#pragma unroll
                for (int c = 0; c < 8; ++c) acc[i][c] = bias[c];

#pragma unroll
            for (int dy = -1; dy <= 1; ++dy) {
                const int y = hh + dy;
                if (y < 0 || y >= Hc) continue;      // block-uniform
                const unsigned short* rp = h1 + ((size_t)bb * Nc + (size_t)y * Wc) * Cc + c0;
                float in[6][8];
#pragma unroll
                for (int dx = 0; dx < 6; ++dx) {
                    const int w = wbase + dx;
                    ushort8 raw = {0, 0, 0, 0, 0, 0, 0, 0};
                    if (w >= 0 && w < Wc) raw = *(const ushort8*)(rp + (size_t)w * Cc);
#pragma unroll
                    for (int c = 0; c < 8; ++c) in[dx][c] = bf2f(raw[c]);
                }
#pragma unroll
                for (int i = 0; i < 4; ++i)
#pragma unroll
                    for (int tx = 0; tx < 3; ++tx)
#pragma unroll
                        for (int c = 0; c < 8; ++c)
                            acc[i][c] += in[i + tx][c] * wt[dy + 1][tx][c];
            }

#pragma unroll
            for (int i = 0; i < 4; ++i) {
                float g[8];
#pragma unroll
                for (int c = 0; c < 8; ++c) {
                    const float v = acc[i][c];
                    const float u = v * v;
                    const float a = __builtin_fmaf(0.0713548162f, u, 1.5957691216f);
                    const float e = __expf(v * a);
                    g[c] = v * e * __builtin_amdgcn_rcpf(e + 1.0f);
                }
                uint2 lo, hi;
                lo.x = pk2bf(g[0], g[1]); lo.y = pk2bf(g[2], g[3]);
                hi.x = pk2bf(g[4], g[5]); hi.y = pk2bf(g[6], g[7]);
                const int wo = wbase + 1 + i;
                const int w0 = wo + s0, w1 = wo + s1;
                if ((unsigned)w0 < (unsigned)Wc)
                    *(uint2*)(Ash + w0 * 512 + ((c0 * 2) ^ ((w0 & 7) << 4))) = lo;
                if ((unsigned)w1 < (unsigned)Wc)
                    *(uint2*)(Ash + w1 * 512 + (((c0 + 4) * 2) ^ ((w1 & 7) << 4))) = hi;
            }
        }
    }

    // ---- phase 2: GEMM out = A @ w2b^T + b2 (two 128-col passes) ----
    const int wm = (wave >> 1) * 64, wn = (wave & 1) * 64;
    const int kq = (lane >> 4) * 8;
    const int rr = lane & 15;
    const int xof = (rr & 7) << 4;           // A read-side XOR (lane constant)
    const int idx0 = tid, idx1 = tid + 256;
    const int cq = (lane >> 4) * 4;
    const int cc = lane & 15;

#pragma unroll 1
    for (int pass = 0; pass < 2; ++pass) {
        const int j0 = pass * 128;
        const size_t bro0 = (size_t)(j0 + (idx0 >> 2)) * Cc + (idx0 & 3) * 8;
        const size_t bro1 = (size_t)(j0 + (idx1 >> 2)) * Cc + (idx1 & 3) * 8;

        auto stageB = [&](int buf, int t) {
            const int k0 = t * 32;
            __bf16* bdst = Bs + buf * 4096;
            async16(w2b + bro0 + k0, bdst + idx0 * 8);
            async16(w2b + bro1 + k0, bdst + idx1 * 8);
        };

        f32x4 acc[4][4] = {};
        stageB(0, 0);
        __syncthreads();    // phase boundary: A scatter + B(0) both land

        int cur = 0;
        for (int t = 0; t < 8; ++t) {
            const int nxt = cur ^ 1;
            if (t < 7) stageB(nxt, t + 1);
            const int k0 = t * 32;
            bf16x8 a[4], b[4];
            const __bf16* bp = Bs + cur * 4096;
#pragma unroll
            for (int i = 0; i < 4; ++i) {
                a[i] = *(const bf16x8*)(Ash + (wm + i * 16 + rr) * 512 + (((k0 + kq) * 2) ^ xof));
                b[i] = *(const bf16x8*)(bp + (wn + i * 16 + rr) * 32 + kq);
            }
#pragma unroll
            for (int i = 0; i < 4; ++i)
#pragma unroll
                for (int j = 0; j < 4; ++j)
                    acc[i][j] = __builtin_amdgcn_mfma_f32_16x16x32_bf16(a[i], b[j], acc[i][j], 0, 0, 0);
            __syncthreads();
            cur = nxt;
        }

        float bv[4];
#pragma unroll
        for (int j = 0; j < 4; ++j) bv[j] = b2[j0 + wn + j * 16 + cc];
#pragma unroll
        for (int i = 0; i < 4; ++i)
#pragma unroll
            for (int j = 0; j < 4; ++j) {
                const int col = j0 + wn + j * 16 + cc;
#pragma unroll
                for (int rg = 0; rg < 4; ++rg)
                    out[(m0 + wm + i * 16 + cq + rg) * Cc + col] = acc[i][j][rg] + bv[j];
            }
    }
}

extern "C" void kernel_launch(void* const* d_in, const int* in_sizes, int n_in,
                              void* d_out, int out_size, void* d_ws, size_t ws_size,
                              hipStream_t stream) {
    // inputs: x, H, W, w1, b1, dw_w, dw_b, w2, b2
    const float* x    = (const float*)d_in[0];
    const float* w1   = (const float*)d_in[3];
    const float* b1   = (const float*)d_in[4];
    const float* dw_w = (const float*)d_in[5];
    const float* dw_b = (const float*)d_in[6];
    const float* w2   = (const float*)d_in[7];
    const float* b2   = (const float*)d_in[8];
    float* out = (float*)d_out;

    // ws layout:
    //   [0,64MB)    h1 bf16
    //   [64,128MB)  xb bf16 (shifted x; only fc1 reads it)
    //   [128MB..)   w1b bf16 (128 KB), w2b bf16 (128 KB), dwT fp32 (9 KB)
    unsigned short* h1  = (unsigned short*)d_ws;
    unsigned short* xb  = h1 + (size_t)Mtot * Cc;
    unsigned short* w1b = xb + (size_t)Mtot * Cc;
    unsigned short* w2b = w1b + 65536;
    float*          dwT = (float*)(w2b + 65536);

    wprep_kernel<<<dim3(64), dim3(256), 0, stream>>>(w1, w2, dw_w, w1b, w2b, dwT);
    shiftcvt_kernel<<<dim3(4096), dim3(256), 0, stream>>>(x, xb);
    fc1_mfma_kernel<<<dim3(2 * Mtot / 128), dim3(256), 0, stream>>>(xb, w1b, b1, h1);
    dwfc2_kernel<<<dim3(Mtot / 128), dim3(256), 0, stream>>>(h1, dwT, dw_b, w2b, b2, out);
}